// Round 16
// baseline (239.164 us; speedup 1.0000x reference)
//
#include <hip/hip_runtime.h>
#include <hip/hip_bf16.h>
#include <stdint.h>

#define HN 128      // hidden size
#define TSTEPS 250
#define ON 20       // output size
#define GK 700      // input size
#define NKT 22      // GEMM k-tiles of 32 (700 = 21*32 + 28, zero-padded)

typedef _Float16 h2 __attribute__((ext_vector_type(2)));
typedef _Float16 h8 __attribute__((ext_vector_type(8)));
typedef float f4 __attribute__((ext_vector_type(4)));

__device__ __forceinline__ uint32_t pack2u(float x, float y) {
    h2 p; p.x = (_Float16)x; p.y = (_Float16)y;
    return __builtin_bit_cast(uint32_t, p);
}

// ---------------------------------------------------------------------------
// Phase A: in1_ff[bt,h] = X[bt,:] . W_ih1[h,:] + b_ih1[h]
// M=64000, N=128, K=700(pad 704). f16 MFMA 16x16x32 (verified r12). FROZEN.
// ---------------------------------------------------------------------------
__global__ __launch_bounds__(256) void ff_gemm(const float* __restrict__ X,
                                               const float* __restrict__ W,
                                               const float* __restrict__ bias,
                                               float* __restrict__ out) {
    __shared__ __align__(16) uint32_t Xs[2][128][16];   // 8 KB x2 (f16 pairs)
    __shared__ __align__(16) uint32_t Ws[2][128][16];   // 8 KB x2
    const int tid   = threadIdx.x;
    const int w     = tid >> 6;
    const int lane  = tid & 63;
    const int m0    = blockIdx.x * 128;
    const int srow  = tid & 127;
    const int shalf = tid >> 7;
    const int lr    = lane & 15;
    const int lg    = lane >> 4;

    f4 acc[2][8];
#pragma unroll
    for (int m = 0; m < 2; ++m)
#pragma unroll
        for (int n = 0; n < 8; ++n) acc[m][n] = (f4){0.f, 0.f, 0.f, 0.f};

    float4 x4[4], w4[4];

#define LOADT(t)                                                               \
    {                                                                          \
        const int k0 = (t) * 32 + shalf * 16;                                  \
        if ((t) < 21 || shalf == 0) {                                          \
            _Pragma("unroll")                                                  \
            for (int q = 0; q < 4; ++q) {                                      \
                x4[q] = *(const float4*)&X[(size_t)(m0 + srow) * GK + k0 + q * 4]; \
                w4[q] = *(const float4*)&W[(size_t)srow * GK + k0 + q * 4];    \
            }                                                                  \
        } else {                                                               \
            _Pragma("unroll")                                                  \
            for (int q = 0; q < 3; ++q) {                                      \
                x4[q] = *(const float4*)&X[(size_t)(m0 + srow) * GK + k0 + q * 4]; \
                w4[q] = *(const float4*)&W[(size_t)srow * GK + k0 + q * 4];    \
            }                                                                  \
            x4[3] = (float4){0.f, 0.f, 0.f, 0.f};                              \
            w4[3] = (float4){0.f, 0.f, 0.f, 0.f};                              \
        }                                                                      \
    }
#define STORET(buf)                                                            \
    {                                                                          \
        _Pragma("unroll")                                                      \
        for (int q = 0; q < 4; ++q) {                                          \
            Xs[buf][srow][shalf * 8 + 2 * q]     = pack2u(x4[q].x, x4[q].y);   \
            Xs[buf][srow][shalf * 8 + 2 * q + 1] = pack2u(x4[q].z, x4[q].w);   \
            Ws[buf][srow][shalf * 8 + 2 * q]     = pack2u(w4[q].x, w4[q].y);   \
            Ws[buf][srow][shalf * 8 + 2 * q + 1] = pack2u(w4[q].z, w4[q].w);   \
        }                                                                      \
    }

    LOADT(0);
    STORET(0);
    __syncthreads();
    int cur = 0;
    for (int t = 0; t < NKT; ++t) {
        if (t + 1 < NKT) LOADT(t + 1);
        h8 a[2];
#pragma unroll
        for (int m = 0; m < 2; ++m) {
            const uint4 au = *(const uint4*)&Xs[cur][w * 32 + m * 16 + lr][lg * 4];
            a[m] = __builtin_bit_cast(h8, au);
        }
#pragma unroll
        for (int n = 0; n < 8; ++n) {
            const uint4 bu = *(const uint4*)&Ws[cur][n * 16 + lr][lg * 4];
            const h8 bf = __builtin_bit_cast(h8, bu);
            acc[0][n] = __builtin_amdgcn_mfma_f32_16x16x32_f16(a[0], bf, acc[0][n], 0, 0, 0);
            acc[1][n] = __builtin_amdgcn_mfma_f32_16x16x32_f16(a[1], bf, acc[1][n], 0, 0, 0);
        }
        if (t + 1 < NKT) STORET(cur ^ 1);
        __syncthreads();
        cur ^= 1;
    }

    float bv[8];
#pragma unroll
    for (int n = 0; n < 8; ++n) bv[n] = bias[n * 16 + lr];
#pragma unroll
    for (int m = 0; m < 2; ++m)
#pragma unroll
        for (int q = 0; q < 4; ++q) {
            const size_t row = (size_t)(m0 + w * 32 + m * 16 + lg * 4 + q);
#pragma unroll
            for (int n = 0; n < 8; ++n)
                out[row * HN + n * 16 + lr] = acc[m][n][q] + bv[n];
        }
#undef LOADT
#undef STORET
}

// ---------------------------------------------------------------------------
// recurrence helpers
// ---------------------------------------------------------------------------
__device__ __forceinline__ void qrow(const float* __restrict__ src,
                                     uint4 (&wq)[8], float& sc) {
    float amax = 0.f;
#pragma unroll
    for (int q = 0; q < 32; ++q) {
        float4 v = *(const float4*)&src[q * 4];
        amax = fmaxf(amax, fmaxf(fmaxf(fabsf(v.x), fabsf(v.y)),
                                 fmaxf(fabsf(v.z), fabsf(v.w))));
    }
    const float qs = (amax > 0.f) ? 127.f / amax : 0.f;
#pragma unroll
    for (int g = 0; g < 8; ++g) {
        uint32_t u[4];
#pragma unroll
        for (int e = 0; e < 4; ++e) {
            float4 v = *(const float4*)&src[g * 16 + e * 4];
            const int q0 = (int)rintf(v.x * qs), q1 = (int)rintf(v.y * qs);
            const int q2 = (int)rintf(v.z * qs), q3 = (int)rintf(v.w * qs);
            u[e] = (uint32_t)(q0 & 255) | ((uint32_t)(q1 & 255) << 8) |
                   ((uint32_t)(q2 & 255) << 16) | ((uint32_t)(q3 & 255) << 24);
        }
        wq[g].x = u[0]; wq[g].y = u[1]; wq[g].z = u[2]; wq[g].w = u[3];
    }
    sc = (amax > 0.f) ? amax / 127.f : 0.f;
}

__device__ __forceinline__ int mvqr(const uint4 (&wq)[8], const uint4 (&sv)[8]) {
    int a0 = 0, a1 = 0, a2 = 0, a3 = 0;
#pragma unroll
    for (int g = 0; g < 8; ++g) {
        a0 = __builtin_amdgcn_sdot4((int)wq[g].x, (int)sv[g].x, a0, false);
        a1 = __builtin_amdgcn_sdot4((int)wq[g].y, (int)sv[g].y, a1, false);
        a2 = __builtin_amdgcn_sdot4((int)wq[g].z, (int)sv[g].z, a2, false);
        a3 = __builtin_amdgcn_sdot4((int)wq[g].w, (int)sv[g].w, a3, false);
    }
    return (a0 + a1) + (a2 + a3);
}

#define LOADQ(arr, buf, sv)                                                    \
    {                                                                          \
        const uint4* _p = (const uint4*)&arr[buf][0];                          \
        _Pragma("unroll") for (int _g = 0; _g < 8; ++_g) sv[_g] = _p[_g];      \
    }

__device__ __forceinline__ uint32_t nib2bytes(uint32_t nib) {
    return ((nib & 15u) * 0x00204081u) & 0x01010101u;
}

// spread a 128-bit spike mask (2x uniform u64 from ballots) into dot-bytes
__device__ __forceinline__ void spread_masks(unsigned long long lo,
                                             unsigned long long hi,
                                             uint4 (&sv)[8]) {
#pragma unroll
    for (int g = 0; g < 8; ++g) {
        const unsigned long long src = (g < 4) ? lo : hi;
        const int base = (g & 3) * 16;
        sv[g].x = nib2bytes((uint32_t)(src >> (base + 0)));
        sv[g].y = nib2bytes((uint32_t)(src >> (base + 4)));
        sv[g].z = nib2bytes((uint32_t)(src >> (base + 8)));
        sv[g].w = nib2bytes((uint32_t)(src >> (base + 12)));
    }
}

// LDS-only fence (do NOT use __threadfence_block: it also drains vmcnt and
// would serialize S1's global ff prefetch)
#define LDS_FENCE() asm volatile("s_waitcnt lgkmcnt(0)" ::: "memory")

#define PROG_S1 0
#define PROG_B  1
#define PROG_C  2
#define PROG_RO 3
#define PROG_OM 4

// ---------------------------------------------------------------------------
// Phase B: DECOUPLED producer/consumer pipeline -- NO per-step barrier.
// 5 waves (320 thr) per batch row. Recurrent deps are wave-internal
// (2 rows/lane + __ballot + SALU spread); cross-stage data flows through
// 8-deep LDS rings guarded by monotonic progress counters (amortized
// polling; lgkmcnt fence before flag publish). Waves slip freely:
//   w0 S1:  s1(t)   <- s1(t-1)[regs], ff(t)          -> s1ring
//   w1 B:   pB(t) = W_h1h2.s1(t)                      -> pBring
//   w2 C:   s2(t)   <- pB(t), s2(t-1)[regs]           -> s2ring
//   w3 RO:  rdot(t) = W_h2o.s2(t)                     -> rdring
//   w4 OM:  om(t), softmax-accumulate (t>10)
// ---------------------------------------------------------------------------
__global__ __launch_bounds__(320) void srnn_pipe12(
    const float* __restrict__ ff,
    const float* __restrict__ W_h1h1, const float* __restrict__ b_h1h1,
    const float* __restrict__ W_h1h2, const float* __restrict__ b_h1h2,
    const float* __restrict__ W_h2h2, const float* __restrict__ b_h2h2,
    const float* __restrict__ W_h2o,  const float* __restrict__ b_h2o,
    const float* __restrict__ tau_adp_h1, const float* __restrict__ tau_adp_h2,
    const float* __restrict__ tau_m_h1,   const float* __restrict__ tau_m_h2,
    const float* __restrict__ tau_m_o,
    const float* __restrict__ h1m0, const float* __restrict__ h2m0,
    const float* __restrict__ om0,
    float* __restrict__ out) {
    const int b    = blockIdx.x;
    const int tid  = threadIdx.x;
    const int w    = tid >> 6;
    const int lane = tid & 63;

    __shared__ __align__(16) uint32_t s1ring[8][32];   // packed spike bytes
    __shared__ __align__(16) uint32_t s2ring[8][32];
    __shared__ __align__(16) float    pBring[8][HN];
    __shared__ __align__(16) float    rdring[8][32];
    __shared__ int prog[8];

    if (tid < 8) prog[tid] = 0;
    __syncthreads();   // the ONLY barrier

#define WAIT_GE(idx, target, cache)                                            \
    if ((cache) < (target)) {                                                  \
        volatile int* _p = (volatile int*)&prog[idx];                          \
        int _v = *_p;                                                          \
        while (_v < (target)) _v = *_p;                                        \
        (cache) = _v;                                                          \
        LDS_FENCE();                                                           \
    }
#define PUBLISH(idx, val)                                                      \
    {                                                                          \
        LDS_FENCE();                                                           \
        if (lane == 0) ((volatile int*)prog)[idx] = (val);                     \
    }

    if (w == 0) {
        // ================= S1: rows lane, lane+64 =========================
        const int jl = lane, jh = lane + 64;
        uint4 wql[8], wqh[8]; float sAl, sAh;
        qrow(W_h1h1 + jl * HN, wql, sAl);
        qrow(W_h1h1 + jh * HN, wqh, sAh);
        float h1m_l = h1m0[b * HN + jl], h1m_h = h1m0[b * HN + jh];
        const float a1l = expf(-1.f / tau_m_h1[jl]), a1h = expf(-1.f / tau_m_h1[jh]);
        const float r1l = expf(-1.f / tau_adp_h1[jl]), r1h = expf(-1.f / tau_adp_h1[jh]);
        const float bil = b_h1h1[jl], bih = b_h1h1[jh];
        float b1l = 0.01f, b1h = 0.01f, s1l = 0.f, s1h = 0.f;
        const float* fpl = ff + (size_t)b * TSTEPS * HN + jl;
        const float* fph = ff + (size_t)b * TSTEPS * HN + jh;
        float fcl = fpl[0], fnl = fpl[HN];
        float fch = fph[0], fnh = fph[HN];
        unsigned long long mklo = 0ull, mkhi = 0ull;
        int cB = 0;
        for (int t = 0; t < TSTEPS; ++t) {
            const float f2l = (t + 2 < TSTEPS) ? fpl[(size_t)(t + 2) * HN] : 0.f;
            const float f2h = (t + 2 < TSTEPS) ? fph[(size_t)(t + 2) * HN] : 0.f;
            uint4 sv[8];
            spread_masks(mklo, mkhi, sv);          // s1(t-1), SALU spread
            const float pAl = sAl * (float)mvqr(wql, sv);
            const float pAh = sAh * (float)mvqr(wqh, sv);
            b1l = r1l * b1l + (1.f - r1l) * s1l;
            b1h = r1h * b1h + (1.f - r1h) * s1h;
            const float Btl = 0.01f + 1.8f * b1l;
            const float Bth = 0.01f + 1.8f * b1h;
            h1m_l = h1m_l * a1l + (1.f - a1l) * (fcl + bil + pAl) - Btl * s1l;
            h1m_h = h1m_h * a1h + (1.f - a1h) * (fch + bih + pAh) - Bth * s1h;
            const int spl = (h1m_l - Btl > 0.f) ? 1 : 0;
            const int sph = (h1m_h - Bth > 0.f) ? 1 : 0;
            s1l = (float)spl; s1h = (float)sph;
            mklo = __ballot(spl); mkhi = __ballot(sph);
            WAIT_GE(PROG_B, t - 7, cB);            // ring back-pressure
            if (lane < 32) {
                const unsigned long long src = (lane < 16) ? mklo : mkhi;
                s1ring[t & 7][lane] = nib2bytes((uint32_t)(src >> ((lane & 15) * 4)));
            }
            PUBLISH(PROG_S1, t + 1);
            fcl = fnl; fnl = f2l; fch = fnh; fnh = f2h;
        }
    } else if (w == 1) {
        // ================= B: pB(t) = W_h1h2 . s1(t) ======================
        const int jl = lane, jh = lane + 64;
        uint4 wql[8], wqh[8]; float sBl, sBh;
        qrow(W_h1h2 + jl * HN, wql, sBl);
        qrow(W_h1h2 + jh * HN, wqh, sBh);
        int cS1 = 0, cC = 0;
        for (int t = 0; t < TSTEPS; ++t) {
            WAIT_GE(PROG_S1, t + 1, cS1);
            uint4 sv[8];
            LOADQ(s1ring, t & 7, sv);
            const float pl = sBl * (float)mvqr(wql, sv);
            const float ph = sBh * (float)mvqr(wqh, sv);
            WAIT_GE(PROG_C, t - 7, cC);
            pBring[t & 7][jl] = pl;
            pBring[t & 7][jh] = ph;
            PUBLISH(PROG_B, t + 1);
        }
    } else if (w == 2) {
        // ================= C+LIF2: s2(t) <- pB(t), s2(t-1) ================
        const int jl = lane, jh = lane + 64;
        uint4 wql[8], wqh[8]; float sCl, sCh;
        qrow(W_h2h2 + jl * HN, wql, sCl);
        qrow(W_h2h2 + jh * HN, wqh, sCh);
        float h2m_l = h2m0[b * HN + jl], h2m_h = h2m0[b * HN + jh];
        const float a2l = expf(-1.f / tau_m_h2[jl]), a2h = expf(-1.f / tau_m_h2[jh]);
        const float r2l = expf(-1.f / tau_adp_h2[jl]), r2h = expf(-1.f / tau_adp_h2[jh]);
        const float bil = b_h1h2[jl] + b_h2h2[jl];
        const float bih = b_h1h2[jh] + b_h2h2[jh];
        float b2l = 0.01f, b2h = 0.01f, s2l = 0.f, s2h = 0.f;
        unsigned long long mklo = 0ull, mkhi = 0ull;
        int cB = 0, cRO = 0;
        for (int t = 0; t < TSTEPS; ++t) {
            uint4 sv[8];
            spread_masks(mklo, mkhi, sv);          // s2(t-1), SALU spread
            const float pCl = sCl * (float)mvqr(wql, sv);
            const float pCh = sCh * (float)mvqr(wqh, sv);
            WAIT_GE(PROG_B, t + 1, cB);
            const float pBl = pBring[t & 7][jl];
            const float pBh = pBring[t & 7][jh];
            b2l = r2l * b2l + (1.f - r2l) * s2l;
            b2h = r2h * b2h + (1.f - r2h) * s2h;
            const float Btl = 0.01f + 1.8f * b2l;
            const float Bth = 0.01f + 1.8f * b2h;
            h2m_l = h2m_l * a2l + (1.f - a2l) * (pBl + pCl + bil) - Btl * s2l;
            h2m_h = h2m_h * a2h + (1.f - a2h) * (pBh + pCh + bih) - Bth * s2h;
            const int spl = (h2m_l - Btl > 0.f) ? 1 : 0;
            const int sph = (h2m_h - Bth > 0.f) ? 1 : 0;
            s2l = (float)spl; s2h = (float)sph;
            mklo = __ballot(spl); mkhi = __ballot(sph);
            WAIT_GE(PROG_RO, t - 7, cRO);
            if (lane < 32) {
                const unsigned long long src = (lane < 16) ? mklo : mkhi;
                s2ring[t & 7][lane] = nib2bytes((uint32_t)(src >> ((lane & 15) * 4)));
            }
            PUBLISH(PROG_C, t + 1);
        }
    } else if (w == 3) {
        // ================= RO: rdot(t) = W_h2o . s2(t) ====================
        const int o = lane;
        uint4 wq[8]; float sO;
        qrow(W_h2o + (size_t)((o < ON) ? o : 0) * HN, wq, sO);
        if (o >= ON) sO = 0.f;
        int cC = 0, cOM = 0;
        for (int t = 0; t < TSTEPS; ++t) {
            WAIT_GE(PROG_C, t + 1, cC);
            uint4 sv[8];
            LOADQ(s2ring, t & 7, sv);
            const float r = sO * (float)mvqr(wq, sv);
            WAIT_GE(PROG_OM, t - 7, cOM);
            if (o < 32) rdring[t & 7][o] = (o < ON) ? r : 0.f;
            PUBLISH(PROG_RO, t + 1);
        }
    } else {
        // ================= OM: redundant register softmax =================
        float omv[ON], accv[ON], aov[ON], bov[ON];
#pragma unroll
        for (int k = 0; k < ON; ++k) {
            omv[k]  = om0[b * ON + k];
            aov[k]  = expf(-1.f / tau_m_o[k]);
            bov[k]  = b_h2o[k];
            accv[k] = 0.f;
        }
        int cRO = 0;
        for (int t = 0; t < TSTEPS; ++t) {
            WAIT_GE(PROG_RO, t + 1, cRO);
            const float4* rp = (const float4*)&rdring[t & 7][0];
            const float4 r0 = rp[0], r1 = rp[1], r2 = rp[2], r3 = rp[3], r4 = rp[4];
            float rd[ON];
            rd[0] = r0.x;  rd[1] = r0.y;  rd[2] = r0.z;  rd[3] = r0.w;
            rd[4] = r1.x;  rd[5] = r1.y;  rd[6] = r1.z;  rd[7] = r1.w;
            rd[8] = r2.x;  rd[9] = r2.y;  rd[10] = r2.z; rd[11] = r2.w;
            rd[12] = r3.x; rd[13] = r3.y; rd[14] = r3.z; rd[15] = r3.w;
            rd[16] = r4.x; rd[17] = r4.y; rd[18] = r4.z; rd[19] = r4.w;
            PUBLISH(PROG_OM, t + 1);   // ring slot consumed (reads drained)
#pragma unroll
            for (int k = 0; k < ON; ++k)
                omv[k] = omv[k] * aov[k] + (1.f - aov[k]) * (rd[k] + bov[k]);
            float m0 = omv[0], m1 = omv[1], m2 = omv[2], m3 = omv[3];
#pragma unroll
            for (int k = 4; k < ON; k += 4) {
                m0 = fmaxf(m0, omv[k]);
                m1 = fmaxf(m1, omv[k + 1]);
                m2 = fmaxf(m2, omv[k + 2]);
                m3 = fmaxf(m3, omv[k + 3]);
            }
            const float mx = fmaxf(fmaxf(m0, m1), fmaxf(m2, m3));
            float e[ON];
            float d0 = 0.f, d1 = 0.f, d2 = 0.f, d3 = 0.f;
#pragma unroll
            for (int k = 0; k < ON; k += 4) {
                e[k]     = __expf(omv[k] - mx);     d0 += e[k];
                e[k + 1] = __expf(omv[k + 1] - mx); d1 += e[k + 1];
                e[k + 2] = __expf(omv[k + 2] - mx); d2 += e[k + 2];
                e[k + 3] = __expf(omv[k + 3] - mx); d3 += e[k + 3];
            }
            const float den = (d0 + d1) + (d2 + d3);
            if (t > 10) {
                const float rden = 1.f / den;
#pragma unroll
                for (int k = 0; k < ON; ++k)
                    accv[k] = fmaf(e[k], rden, accv[k]);
            }
        }
        if (lane == 0) {
#pragma unroll
            for (int k = 0; k < ON; ++k) out[b * ON + k] = accv[k];
        }
    }
#undef WAIT_GE
#undef PUBLISH
}

// ---------------------------------------------------------------------------
// Phase C: A_norm = sum|W_h1h1| + sum|W_h2h2|  -> out[5120]  (exact fp32)
// ---------------------------------------------------------------------------
__global__ void anorm_kernel(const float* __restrict__ W1,
                             const float* __restrict__ W2,
                             float* __restrict__ out) {
    __shared__ float red[256];
    float s = 0.f;
    for (int i = threadIdx.x; i < HN * HN; i += 256)
        s += fabsf(W1[i]) + fabsf(W2[i]);
    red[threadIdx.x] = s;
    __syncthreads();
    for (int off = 128; off > 0; off >>= 1) {
        if (threadIdx.x < off) red[threadIdx.x] += red[threadIdx.x + off];
        __syncthreads();
    }
    if (threadIdx.x == 0) out[256 * ON] = red[0];
}

extern "C" void kernel_launch(void* const* d_in, const int* in_sizes, int n_in,
                              void* d_out, int out_size, void* d_ws, size_t ws_size,
                              hipStream_t stream) {
    const float* input      = (const float*)d_in[0];
    // d_in[1], d_in[2]: A1_mask/A2_mask -- all-ones, unused by reference math
    const float* W_ih1      = (const float*)d_in[3];
    const float* b_ih1      = (const float*)d_in[4];
    const float* W_h1h1     = (const float*)d_in[5];
    const float* b_h1h1     = (const float*)d_in[6];
    const float* W_h1h2     = (const float*)d_in[7];
    const float* b_h1h2     = (const float*)d_in[8];
    const float* W_h2h2     = (const float*)d_in[9];
    const float* b_h2h2     = (const float*)d_in[10];
    const float* W_h2o      = (const float*)d_in[11];
    const float* b_h2o      = (const float*)d_in[12];
    const float* tau_adp_h1 = (const float*)d_in[13];
    const float* tau_adp_h2 = (const float*)d_in[14];
    const float* tau_m_h1   = (const float*)d_in[15];
    const float* tau_m_h2   = (const float*)d_in[16];
    const float* tau_m_o    = (const float*)d_in[17];
    const float* h1m0       = (const float*)d_in[18];
    const float* h2m0       = (const float*)d_in[19];
    const float* om0        = (const float*)d_in[20];

    float* out   = (float*)d_out;
    float* ffbuf = (float*)d_ws;   // 256*250*128*4 = 32.768 MB

    anorm_kernel<<<1, 256, 0, stream>>>(W_h1h1, W_h2h2, out);
    ff_gemm<<<500, 256, 0, stream>>>(input, W_ih1, b_ih1, ffbuf);
    srnn_pipe12<<<256, 320, 0, stream>>>(ffbuf, W_h1h1, b_h1h1, W_h1h2, b_h1h2,
                                         W_h2h2, b_h2h2, W_h2o, b_h2o,
                                         tau_adp_h1, tau_adp_h2,
                                         tau_m_h1, tau_m_h2, tau_m_o,
                                         h1m0, h2m0, om0, out);
}